// Round 16
// baseline (39.229 us; speedup 1.0000x reference)
//
#include <hip/hip_runtime.h>
#include <stdint.h>

typedef __attribute__((ext_vector_type(8))) __bf16 bf16x8;
typedef __attribute__((ext_vector_type(4))) __bf16 bf16x4;
typedef __attribute__((ext_vector_type(4))) float f32x4;

#define MFMA_BF16(A, B, C) __builtin_amdgcn_mfma_f32_16x16x32_bf16((A), (B), (C), 0, 0, 0)
// end-of-tile barrier: own DMA done (vmcnt) + own LDS reads done (lgkm) + all waves
#define VBAR() asm volatile("s_waitcnt vmcnt(0) lgkmcnt(0)\ns_barrier" ::: "memory")

// async 16B/lane global->LDS: per-lane gsrc, wave-uniform LDS base (+lane*16 by HW)
__device__ __forceinline__ void gload16(const void* g, void* l) {
  __builtin_amdgcn_global_load_lds((const __attribute__((address_space(1))) void*)g,
                                   (__attribute__((address_space(3))) void*)l, 16, 0, 0);
}

namespace {

constexpr int kBatch = 8;
constexpr int kL = 4096;
constexpr int kD = 64;
constexpr int kQB = 128;        // queries per attn block (4 waves x 2 halves x 16)
constexpr int kKB = 64;         // keys per tile
constexpr int kSlotPad = 4096;  // xch slot capacity (fallback-safe)
constexpr int kMaxTiles = 64;   // vtg tile capacity (fallback-safe)
constexpr int kSlotCap = 2304;  // pl/pacc capacity per (split,batch) (count~2048+-32)
constexpr int kSplits = 8;      // A/B vs r15's 4: 1024 attn blocks = 4/CU = 2x occupancy
// exp2-domain scale: log2(e) / D^0.25  (scores bounded -> fixed-max m=0 is safe)
constexpr float kC = 1.4426950408889634f / 2.8284271247461903f;

// workspace layout (bytes); ws_size ~268MB (round-7 fill evidence)
constexpr size_t kWsPartialOff = 0;        // float[8][32][64]
constexpr size_t kWsCountOff = 65536;      // int[8]
constexpr size_t kWsRankOff = 131136;      // uint16_t[8][4096]  row -> slot
constexpr size_t kWsPlOff = 196672;        // float[S][8][2304]
constexpr size_t kWsXchOff = 1376320;      // __bf16[8][4096][64] = 4194304
constexpr size_t kWsVtgOff = 5570624;      // __bf16[8][64][64][64] = 4194304
constexpr size_t kWsPaccOff = 9764928;     // __bf16[S][8][2304][64] -> end 28.6MB @ S=8

// K-row unit swizzle: spreads the 16 QK A-frag rows per quarter-wave over 8 bank-quads
__device__ __forceinline__ int fk(int r) { return (r & 3) | ((r >> 1) & 4); }

// pacc/pl slot-row; fallback (fb) = any count > kSlotCap -> S=1, stride kL
__device__ __forceinline__ size_t slotrow(int s, int b, int slot, bool fb) {
  return fb ? ((size_t)b * kL + slot) : ((size_t)(s * kBatch + b) * kSlotCap + slot);
}

__device__ __forceinline__ float bf16hi_f(uint32_t u) { return __uint_as_float(u << 16); }

// ---------------- kernel 1: self-sufficient compact+convert | colsum ---------
// blocks x<64: tile x of batch y — recompute mask prefix-scan locally (wave
// shfl scan, 2 block barriers total), build slot->row table, gather+convert
// rows to bf16 K-store (xch, fk-swizzled) and V^T-store (vtg, d&7-swizzled).
// Block x==0 also publishes rank[] and counts[].
// blocks x in [64,96): column partial sums for the batch mean.
__global__ __launch_bounds__(256) void k_prep(const float* __restrict__ x,
                                              const int* __restrict__ mask,
                                              float* __restrict__ partial,
                                              uint16_t* __restrict__ rank,
                                              int* __restrict__ counts,
                                              __bf16* __restrict__ xch,
                                              __bf16* __restrict__ vtg) {
  const int b = blockIdx.y;
  const int bx = blockIdx.x;
  const int t = threadIdx.x;

  if (bx >= 64) {  // ---- colsum: rows [part*128, part*128+128) ----
    const int part = bx - 64;
    __shared__ float sm[256];
    const int d = t & 63, rs = t >> 6;
    const float* xb = x + (size_t)b * kL * kD;
    float s = 0.0f;
    const int r0 = part * 128 + rs;
    for (int i = 0; i < 32; ++i) s += xb[(size_t)(r0 + i * 4) * kD + d];
    sm[t] = s;
    __syncthreads();
    if (t < 64)
      partial[(b * 32 + part) * 64 + t] = sm[t] + sm[t + 64] + sm[t + 128] + sm[t + 192];
    return;
  }

  // ---- per-block mask prefix-scan (wave shfl; redundant across blocks) ----
  __shared__ int wsum[4];
  __shared__ int slotTab[64];  // slot -> original row; -1 = zero-fill pad
  __shared__ __align__(16) __bf16 tmp[kKB][80];

  const int lane = t & 63, wave = t >> 6;
  const int* mb = mask + b * kL;
  const int r0 = t * 16;
  int msk16 = 0, cnt = 0;
#pragma unroll
  for (int i = 0; i < 16; ++i) {
    if (mb[r0 + i] != 0) { msk16 |= 1 << i; ++cnt; }
  }
  if (t < 64) slotTab[t] = -1;

  int incl = cnt;  // wave-level inclusive scan (no barriers)
#pragma unroll
  for (int off = 1; off < 64; off <<= 1) {
    const int up = __shfl_up(incl, off);
    if (lane >= off) incl += up;
  }
  if (lane == 63) wsum[wave] = incl;
  __syncthreads();
  int waveoff = 0;
#pragma unroll
  for (int w = 0; w < 4; ++w) waveoff += (w < wave) ? wsum[w] : 0;
  const int count = wsum[0] + wsum[1] + wsum[2] + wsum[3];
  const int excl0 = waveoff + incl - cnt;  // exclusive prefix for this thread

  const int base = bx * 64;
  {
    int rk = excl0;
#pragma unroll
    for (int i = 0; i < 16; ++i) {
      if (msk16 & (1 << i)) {
        if (rk >= base && rk < base + 64) slotTab[rk - base] = r0 + i;
        ++rk;
      }
    }
  }
  if (bx == 0) {  // publish rank + counts once per batch
    int rk = excl0;
#pragma unroll
    for (int i = 0; i < 16; ++i) {
      if (msk16 & (1 << i)) { rank[b * kL + r0 + i] = (uint16_t)rk; ++rk; }
    }
    if (t == 0) counts[b] = count;
  }
  __syncthreads();

  const int NT = (count + kKB - 1) >> 6;
  if (bx >= NT) return;

  // ---- gather + convert + transpose for tile bx ----
  const int srow = t >> 2, q3 = t & 3;
  const int slot = base + srow;
  const int rowi = slotTab[srow];
  float v16[16];
  if (rowi >= 0) {
    const float4* p = (const float4*)(x + ((size_t)b * kL + rowi) * kD + q3 * 16);
    const float4 a0 = p[0], a1 = p[1], a2 = p[2], a3 = p[3];
    v16[0] = a0.x; v16[1] = a0.y; v16[2] = a0.z; v16[3] = a0.w;
    v16[4] = a1.x; v16[5] = a1.y; v16[6] = a1.z; v16[7] = a1.w;
    v16[8] = a2.x; v16[9] = a2.y; v16[10] = a2.z; v16[11] = a2.w;
    v16[12] = a3.x; v16[13] = a3.y; v16[14] = a3.z; v16[15] = a3.w;
  } else {
#pragma unroll
    for (int i = 0; i < 16; ++i) v16[i] = 0.0f;
  }
  bf16x8 u0, u1;
#pragma unroll
  for (int j = 0; j < 8; ++j) { u0[j] = (__bf16)v16[j]; u1[j] = (__bf16)v16[8 + j]; }

  {  // K-store write (unit-swizzled)
    __bf16* xrow = xch + ((size_t)b * kSlotPad + slot) * kD;
    const int f = fk(srow);
    *(bf16x8*)(xrow + (((2 * q3) ^ f) << 3)) = u0;
    *(bf16x8*)(xrow + (((2 * q3 + 1) ^ f) << 3)) = u1;
  }
  *(bf16x8*)&tmp[srow][q3 * 16] = u0;
  *(bf16x8*)&tmp[srow][q3 * 16 + 8] = u1;
  __syncthreads();
  {  // V^T write: thread -> (d = t>>2, k-quarter kq = t&3)
    const int d = t >> 2, kq = t & 3;
    bf16x8 c0, c1;
#pragma unroll
    for (int i = 0; i < 8; ++i) {
      c0[i] = tmp[kq * 16 + i][d];
      c1[i] = tmp[kq * 16 + 8 + i][d];
    }
    __bf16* vrow = vtg + (((size_t)b * kMaxTiles + bx) * kKB + d) * kD;
    const int e = d & 7;
    *(bf16x8*)(vrow + (((2 * kq) ^ e) << 3)) = c0;
    *(bf16x8*)(vrow + (((2 * kq + 1) ^ e) << 3)) = c1;
  }
}

// ---------------- kernel 2: split-K flash attention, QB=128, fixed-max -------
// grid = (batch, split, qt): batch == blockIdx.x pins each batch to one XCD.
// Each wave serves 2 query-halves; every K/V A-frag LDS read feeds 2 MFMAs.
// Softmax denominator accumulated via ones-row MFMA (no VALU reduction).
__global__ __launch_bounds__(256, 4) void k_attn(const __bf16* __restrict__ xch,
                                                 const __bf16* __restrict__ vtg,
                                                 const int* __restrict__ counts,
                                                 float* __restrict__ pl,
                                                 __bf16* __restrict__ pacc) {
  const int b = blockIdx.x;
  const int s = blockIdx.y;
  const int qt = blockIdx.z;

  int cmax = 0;
#pragma unroll
  for (int i = 0; i < kBatch; ++i) cmax = max(cmax, counts[i]);
  const bool fb = cmax > kSlotCap;  // astronomically unlikely guard
  const int nS = fb ? 1 : (int)gridDim.y;
  if (fb && s > 0) return;

  const int count = counts[b];
  if (qt * kQB >= count) return;
  const int NTtot = (count + kKB - 1) >> 6;
  const int TPS = (NTtot + nS - 1) / nS;
  const int t0 = s * TPS;
  const int t1 = min(NTtot, t0 + TPS);

  const int tid = threadIdx.x;
  const int wave = tid >> 6;
  const int lane = tid & 63;
  const int lg = lane >> 4;  // lane group 0..3
  const int lr = lane & 15;  // lane row/col 0..15

  int qpos[2];
  bool qvalid[2];
  size_t sr[2];
#pragma unroll
  for (int h = 0; h < 2; ++h) {
    qpos[h] = qt * kQB + h * 64 + wave * 16 + lr;
    qvalid[h] = qpos[h] < count;
    sr[h] = slotrow(s, b, qpos[h], fb);
  }

  if (t0 >= t1) {  // empty split: identity partial (l=0, acc=0)
#pragma unroll
    for (int h = 0; h < 2; ++h) {
      if (qvalid[h]) {
        const bf16x4 z = (bf16x4)(__bf16)0.0f;
#pragma unroll
        for (int dt = 0; dt < 4; ++dt) *(bf16x4*)&pacc[sr[h] * kD + dt * 16 + lg * 4] = z;
        if (lg == 0) pl[sr[h]] = 0.0f;
      }
    }
    return;
  }

  const __bf16* __restrict__ xb = xch + (size_t)b * kSlotPad * kD;
  const __bf16* __restrict__ vb = vtg + (size_t)b * kMaxTiles * (kKB * kD);

  __shared__ __align__(16) __bf16 KhB[2][kKB * kD];  // K tiles (double buffer)
  __shared__ __align__(16) __bf16 VtB[2][kKB * kD];  // V^T tiles (double buffer)

  // ---- Q B-frags: lane holds Q[q][d=kt*32+lg*8+j] for both halves
  bf16x8 qh[2][2];
#pragma unroll
  for (int h = 0; h < 2; ++h) {
    const int qr = qvalid[h] ? qpos[h] : 0;
    const __bf16* qrow = xb + (size_t)qr * kD;
    const int f = fk(qr & 63);
#pragma unroll
    for (int kt = 0; kt < 2; ++kt)
      qh[h][kt] = *(const bf16x8*)(qrow + (((kt * 4 + lg) ^ f) << 3));
  }

  f32x4 acc[2][4];  // out^T per half: lane holds d = dt*16+4*lg+r, col q=lr
  f32x4 acc_l[2];   // denom via ones-row MFMA: row0 (lg==0) = sum_k p[k][q=lr]
#pragma unroll
  for (int h = 0; h < 2; ++h) {
#pragma unroll
    for (int i = 0; i < 4; ++i) acc[h][i] = (f32x4)0.0f;
    acc_l[h] = (f32x4)0.0f;
  }

  bf16x8 vone;  // ones-row A-frag
#pragma unroll
  for (int j = 0; j < 8; ++j) vone[j] = (lr == 0) ? (__bf16)1.0f : (__bf16)0.0f;

  // async staging: wave covers 2KB of each 8KB tile (2 x 1KB chunks per buffer)
  auto stage = [&](int t, int buf) {
    const size_t goff = (size_t)t * (kKB * kD);
    const int lo = lane * 8;
#pragma unroll
    for (int c = 0; c < 2; ++c) {
      const int eo = wave * 1024 + c * 512;
      gload16(xb + goff + eo + lo, &KhB[buf][eo]);
      gload16(vb + goff + eo + lo, &VtB[buf][eo]);
    }
  };

  stage(t0, 0);
  VBAR();

  int cur = 0;
  for (int t = t0; t < t1; ++t) {
    const bool havenext = (t + 1 < t1);
    if (havenext) stage(t + 1, cur ^ 1);  // DMA lands during compute

    const __bf16* Kh = &KhB[cur][0];
    const __bf16* Vt = &VtB[cur][0];

    // ---- QK: S' = K * Q^T; each ah feeds both halves
    f32x4 S_[2][2][2];  // [h][g][tt]
    __builtin_amdgcn_s_setprio(1);
#pragma unroll
    for (int g = 0; g < 2; ++g) {
#pragma unroll
      for (int tt = 0; tt < 2; ++tt) {
        const int krow = g * 32 + ((lr >> 2) << 3) + tt * 4 + (lr & 3);
        const int f = fk(krow);
        f32x4 s0 = (f32x4)0.0f, s1 = (f32x4)0.0f;
#pragma unroll
        for (int kt = 0; kt < 2; ++kt) {
          const bf16x8 ah = *(const bf16x8*)&Kh[(krow << 6) + (((kt * 4 + lg) ^ f) << 3)];
          s0 = MFMA_BF16(ah, qh[0][kt], s0);
          s1 = MFMA_BF16(ah, qh[1][kt], s1);
        }
        S_[0][g][tt] = s0;
        S_[1][g][tt] = s1;
      }
    }
    __builtin_amdgcn_s_setprio(0);

    // ---- fixed-max softmax: p = 2^(s*kC) (scores bounded; no max tracking)
    float p[2][2][2][4];
#pragma unroll
    for (int h = 0; h < 2; ++h)
#pragma unroll
      for (int g = 0; g < 2; ++g)
#pragma unroll
        for (int tt = 0; tt < 2; ++tt)
#pragma unroll
          for (int r = 0; r < 4; ++r)
            p[h][g][tt][r] = __builtin_amdgcn_exp2f(S_[h][g][tt][r] * kC);

    if (t == NTtot - 1 && (count & 63)) {  // zero-padded keys on last tile
      const int valid = count & 63;
#pragma unroll
      for (int h = 0; h < 2; ++h)
#pragma unroll
        for (int g = 0; g < 2; ++g)
#pragma unroll
          for (int tt = 0; tt < 2; ++tt)
#pragma unroll
            for (int r = 0; r < 4; ++r) {
              const int kl2 = g * 32 + lg * 8 + tt * 4 + r;
              if (kl2 >= valid) p[h][g][tt][r] = 0.0f;
            }
    }

    bf16x8 pf[2][2];  // [h][g]
#pragma unroll
    for (int h = 0; h < 2; ++h)
#pragma unroll
      for (int g = 0; g < 2; ++g)
#pragma unroll
        for (int tt = 0; tt < 2; ++tt)
#pragma unroll
          for (int r = 0; r < 4; ++r) pf[h][g][tt * 4 + r] = (__bf16)p[h][g][tt][r];

    // ---- PV: out^T += V^T * P'; denom via ones-row MFMA
    __builtin_amdgcn_s_setprio(1);
#pragma unroll
    for (int g = 0; g < 2; ++g) {
      acc_l[0] = MFMA_BF16(vone, pf[0][g], acc_l[0]);
      acc_l[1] = MFMA_BF16(vone, pf[1][g], acc_l[1]);
#pragma unroll
      for (int dt = 0; dt < 4; ++dt) {
        const int d = dt * 16 + lr;
        const bf16x8 vf =
            *(const bf16x8*)&Vt[(d << 6) + ((((g << 2) + lg) ^ (d & 7)) << 3)];
        acc[0][dt] = MFMA_BF16(vf, pf[0][g], acc[0][dt]);
        acc[1][dt] = MFMA_BF16(vf, pf[1][g], acc[1][dt]);
      }
    }
    __builtin_amdgcn_s_setprio(0);

    if (havenext) VBAR();  // DMA for t+1 complete + all waves done with cur
    cur ^= 1;
  }

  // ---- epilogue: bf16 partial acc + denom per half
#pragma unroll
  for (int h = 0; h < 2; ++h) {
    if (qvalid[h]) {
#pragma unroll
      for (int dt = 0; dt < 4; ++dt) {
        bf16x4 v;
#pragma unroll
        for (int r = 0; r < 4; ++r) v[r] = (__bf16)acc[h][dt][r];
        *(bf16x4*)&pacc[sr[h] * kD + dt * 16 + lg * 4] = v;
      }
      if (lg == 0) pl[sr[h]] = acc_l[h][0];
    }
  }
}

// ---------------- kernel 3: fused mean-fill + split-K reduce ------------------
// Fixed-max combine: out = (sum_s acc_s) / (sum_s l_s). Dword pacc loads
// (2 bf16 per load); 8 row-groups x 32 threads; float2 coalesced stores.
template <int TS>
__global__ __launch_bounds__(256) void k_post(const int* __restrict__ mask,
                                              const float* __restrict__ partial,
                                              const uint16_t* __restrict__ rank,
                                              const int* __restrict__ counts,
                                              const float* __restrict__ pl,
                                              const __bf16* __restrict__ pacc,
                                              float* __restrict__ out) {
  const int b = blockIdx.y;
  const int c = blockIdx.x;  // 128 chunks of 32 rows
  const int t = threadIdx.x;

  int cmax = 0;
#pragma unroll
  for (int i = 0; i < kBatch; ++i) cmax = max(cmax, counts[i]);
  const bool fb = cmax > kSlotCap;

  __shared__ float mean[64];
  __shared__ float winv[32];  // 1/L per token
  __shared__ int slotL[32];   // -1 = masked row

  if (t < 64) {  // phase 0: batch column mean
    float s = 0.0f;
    for (int p = 0; p < 32; ++p) s += partial[(b * 32 + p) * 64 + t];
    mean[t] = s * (1.0f / (float)kL);
  } else if (t < 96) {  // phase 1: per-token 1/L
    const int i = t - 64;
    const int r = c * 32 + i;
    if (mask[b * kL + r] == 0) {
      slotL[i] = -1;
    } else {
      const int slot = rank[b * kL + r];
      slotL[i] = slot;
      float L = 0.0f;
      if (!fb) {
#pragma unroll
        for (int s2 = 0; s2 < TS; ++s2)
          L += pl[(size_t)(s2 * kBatch + b) * kSlotCap + slot];
      } else {
        L = pl[(size_t)b * kL + slot];
      }
      winv[i] = 1.0f / L;
    }
  }
  __syncthreads();

  const int d0 = (t & 31) * 2;
  const int rg = t >> 5;  // row-group 0..7
#pragma unroll
  for (int it = 0; it < 4; ++it) {
    const int rl = it * 8 + rg;  // wave-uniform row-in-chunk
    const int slot = slotL[rl];
    float o0, o1;
    if (slot < 0) {
      o0 = mean[d0];
      o1 = mean[d0 + 1];
    } else if (!fb) {
      o0 = 0.0f;
      o1 = 0.0f;
#pragma unroll
      for (int s2 = 0; s2 < TS; ++s2) {
        const uint32_t v = *(const uint32_t*)&pacc[((size_t)(s2 * kBatch + b) * kSlotCap +
                                                    slot) * kD + d0];
        o0 += bf16hi_f(v & 0xFFFFu);
        o1 += bf16hi_f(v >> 16);
      }
      o0 *= winv[rl];
      o1 *= winv[rl];
    } else {
      const uint32_t v = *(const uint32_t*)&pacc[((size_t)b * kL + slot) * kD + d0];
      o0 = winv[rl] * bf16hi_f(v & 0xFFFFu);
      o1 = winv[rl] * bf16hi_f(v >> 16);
    }
    *(float2*)&out[((size_t)b * kL + c * 32 + rl) * kD + d0] = float2{o0, o1};
  }
}

}  // namespace

extern "C" void kernel_launch(void* const* d_in, const int* in_sizes, int n_in,
                              void* d_out, int out_size, void* d_ws, size_t ws_size,
                              hipStream_t stream) {
  const float* x = (const float*)d_in[0];
  const int* mask = (const int*)d_in[1];
  float* out = (float*)d_out;
  char* ws = (char*)d_ws;
  float* partial = (float*)(ws + kWsPartialOff);
  int* counts = (int*)(ws + kWsCountOff);
  uint16_t* rank = (uint16_t*)(ws + kWsRankOff);
  float* pl = (float*)(ws + kWsPlOff);
  __bf16* xch = (__bf16*)(ws + kWsXchOff);
  __bf16* vtg = (__bf16*)(ws + kWsVtgOff);
  __bf16* pacc = (__bf16*)(ws + kWsPaccOff);

  // ws_size ~268MB (round-7 fill evidence); S=8 layout ends at 28.6MB
  int S = kSplits;
  while (S > 1 && ws_size < kWsPaccOff + (size_t)S * kBatch * kSlotCap * kD * 2) S >>= 1;

  k_prep<<<dim3(96, kBatch), dim3(256), 0, stream>>>(x, mask, partial, rank, counts,
                                                     xch, vtg);
  k_attn<<<dim3(kBatch, S, kL / kQB), dim3(256), 0, stream>>>(xch, vtg, counts, pl, pacc);
  switch (S) {
    case 8:
      k_post<8><<<dim3(128, kBatch), dim3(256), 0, stream>>>(mask, partial, rank, counts,
                                                             pl, pacc, out);
      break;
    case 4:
      k_post<4><<<dim3(128, kBatch), dim3(256), 0, stream>>>(mask, partial, rank, counts,
                                                             pl, pacc, out);
      break;
    case 2:
      k_post<2><<<dim3(128, kBatch), dim3(256), 0, stream>>>(mask, partial, rank, counts,
                                                             pl, pacc, out);
      break;
    default:
      k_post<1><<<dim3(128, kBatch), dim3(256), 0, stream>>>(mask, partial, rank, counts,
                                                             pl, pacc, out);
      break;
  }
}

// Round 17
// 37.454 us; speedup vs baseline: 1.0474x; 1.0474x over previous
//
#include <hip/hip_runtime.h>
#include <stdint.h>

typedef __attribute__((ext_vector_type(8))) __bf16 bf16x8;
typedef __attribute__((ext_vector_type(4))) __bf16 bf16x4;
typedef __attribute__((ext_vector_type(4))) float f32x4;

#define MFMA_BF16(A, B, C) __builtin_amdgcn_mfma_f32_16x16x32_bf16((A), (B), (C), 0, 0, 0)
// end-of-tile barrier: own DMA done (vmcnt) + own LDS reads done (lgkm) + all waves
#define VBAR() asm volatile("s_waitcnt vmcnt(0) lgkmcnt(0)\ns_barrier" ::: "memory")

// async 16B/lane global->LDS: per-lane gsrc, wave-uniform LDS base (+lane*16 by HW)
__device__ __forceinline__ void gload16(const void* g, void* l) {
  __builtin_amdgcn_global_load_lds((const __attribute__((address_space(1))) void*)g,
                                   (__attribute__((address_space(3))) void*)l, 16, 0, 0);
}

namespace {

constexpr int kBatch = 8;
constexpr int kL = 4096;
constexpr int kD = 64;
constexpr int kQB = 128;        // queries per attn block (4 waves x 2 halves x 16)
constexpr int kKB = 64;         // keys per tile
constexpr int kSlotPad = 4096;  // xch slot capacity (fallback-safe)
constexpr int kMaxTiles = 64;   // vtg tile capacity (fallback-safe)
constexpr int kSlotCap = 2304;  // pl/pacc capacity per (split,batch) (count~2048+-32)
constexpr int kSplits = 4;      // A/B settled: S=4 (37.5us) < S=8 (39.2us)
// exp2-domain scale: log2(e) / D^0.25  (scores bounded -> fixed-max m=0 is safe)
constexpr float kC = 1.4426950408889634f / 2.8284271247461903f;

// workspace layout (bytes); ws_size ~268MB (round-7 fill evidence)
constexpr size_t kWsPartialOff = 0;        // float[8][32][64]
constexpr size_t kWsCountOff = 65536;      // int[8]
constexpr size_t kWsRankOff = 131136;      // uint16_t[8][4096]  row -> slot
constexpr size_t kWsPlOff = 196672;        // float[S][8][2304]
constexpr size_t kWsXchOff = 1376320;      // __bf16[8][4096][64] = 4194304
constexpr size_t kWsVtgOff = 5570624;      // __bf16[8][64][64][64] = 4194304
constexpr size_t kWsPaccOff = 9764928;     // __bf16[S][8][2304][64]

// K-row unit swizzle: spreads the 16 QK A-frag rows per quarter-wave over 8 bank-quads
__device__ __forceinline__ int fk(int r) { return (r & 3) | ((r >> 1) & 4); }

// pacc/pl slot-row; fallback (fb) = any count > kSlotCap -> S=1, stride kL
__device__ __forceinline__ size_t slotrow(int s, int b, int slot, bool fb) {
  return fb ? ((size_t)b * kL + slot) : ((size_t)(s * kBatch + b) * kSlotCap + slot);
}

__device__ __forceinline__ float bf16hi_f(uint32_t u) { return __uint_as_float(u << 16); }

// ---------------- kernel 1: self-sufficient compact+convert | colsum ---------
// blocks x<64: tile x of batch y — recompute mask prefix-scan locally (wave
// shfl scan, 2 block barriers total), build slot->row table, gather+convert
// rows to bf16 K-store (xch, fk-swizzled) and V^T-store (vtg, d&7-swizzled).
// Block x==0 also publishes rank[] and counts[].
// blocks x in [64,96): column partial sums for the batch mean.
__global__ __launch_bounds__(256) void k_prep(const float* __restrict__ x,
                                              const int* __restrict__ mask,
                                              float* __restrict__ partial,
                                              uint16_t* __restrict__ rank,
                                              int* __restrict__ counts,
                                              __bf16* __restrict__ xch,
                                              __bf16* __restrict__ vtg) {
  const int b = blockIdx.y;
  const int bx = blockIdx.x;
  const int t = threadIdx.x;

  if (bx >= 64) {  // ---- colsum: rows [part*128, part*128+128) ----
    const int part = bx - 64;
    __shared__ float sm[256];
    const int d = t & 63, rs = t >> 6;
    const float* xb = x + (size_t)b * kL * kD;
    float s = 0.0f;
    const int r0 = part * 128 + rs;
    for (int i = 0; i < 32; ++i) s += xb[(size_t)(r0 + i * 4) * kD + d];
    sm[t] = s;
    __syncthreads();
    if (t < 64)
      partial[(b * 32 + part) * 64 + t] = sm[t] + sm[t + 64] + sm[t + 128] + sm[t + 192];
    return;
  }

  // ---- per-block mask prefix-scan (wave shfl; redundant across blocks) ----
  __shared__ int wsum[4];
  __shared__ int slotTab[64];  // slot -> original row; -1 = zero-fill pad
  __shared__ __align__(16) __bf16 tmp[kKB][80];

  const int lane = t & 63, wave = t >> 6;
  const int* mb = mask + b * kL;
  const int r0 = t * 16;
  int msk16 = 0, cnt = 0;
#pragma unroll
  for (int i = 0; i < 16; ++i) {
    if (mb[r0 + i] != 0) { msk16 |= 1 << i; ++cnt; }
  }
  if (t < 64) slotTab[t] = -1;

  int incl = cnt;  // wave-level inclusive scan (no barriers)
#pragma unroll
  for (int off = 1; off < 64; off <<= 1) {
    const int up = __shfl_up(incl, off);
    if (lane >= off) incl += up;
  }
  if (lane == 63) wsum[wave] = incl;
  __syncthreads();
  int waveoff = 0;
#pragma unroll
  for (int w = 0; w < 4; ++w) waveoff += (w < wave) ? wsum[w] : 0;
  const int count = wsum[0] + wsum[1] + wsum[2] + wsum[3];
  const int excl0 = waveoff + incl - cnt;  // exclusive prefix for this thread

  const int base = bx * 64;
  {
    int rk = excl0;
#pragma unroll
    for (int i = 0; i < 16; ++i) {
      if (msk16 & (1 << i)) {
        if (rk >= base && rk < base + 64) slotTab[rk - base] = r0 + i;
        ++rk;
      }
    }
  }
  if (bx == 0) {  // publish rank + counts once per batch
    int rk = excl0;
#pragma unroll
    for (int i = 0; i < 16; ++i) {
      if (msk16 & (1 << i)) { rank[b * kL + r0 + i] = (uint16_t)rk; ++rk; }
    }
    if (t == 0) counts[b] = count;
  }
  __syncthreads();

  const int NT = (count + kKB - 1) >> 6;
  if (bx >= NT) return;

  // ---- gather + convert + transpose for tile bx ----
  const int srow = t >> 2, q3 = t & 3;
  const int slot = base + srow;
  const int rowi = slotTab[srow];
  float v16[16];
  if (rowi >= 0) {
    const float4* p = (const float4*)(x + ((size_t)b * kL + rowi) * kD + q3 * 16);
    const float4 a0 = p[0], a1 = p[1], a2 = p[2], a3 = p[3];
    v16[0] = a0.x; v16[1] = a0.y; v16[2] = a0.z; v16[3] = a0.w;
    v16[4] = a1.x; v16[5] = a1.y; v16[6] = a1.z; v16[7] = a1.w;
    v16[8] = a2.x; v16[9] = a2.y; v16[10] = a2.z; v16[11] = a2.w;
    v16[12] = a3.x; v16[13] = a3.y; v16[14] = a3.z; v16[15] = a3.w;
  } else {
#pragma unroll
    for (int i = 0; i < 16; ++i) v16[i] = 0.0f;
  }
  bf16x8 u0, u1;
#pragma unroll
  for (int j = 0; j < 8; ++j) { u0[j] = (__bf16)v16[j]; u1[j] = (__bf16)v16[8 + j]; }

  {  // K-store write (unit-swizzled)
    __bf16* xrow = xch + ((size_t)b * kSlotPad + slot) * kD;
    const int f = fk(srow);
    *(bf16x8*)(xrow + (((2 * q3) ^ f) << 3)) = u0;
    *(bf16x8*)(xrow + (((2 * q3 + 1) ^ f) << 3)) = u1;
  }
  *(bf16x8*)&tmp[srow][q3 * 16] = u0;
  *(bf16x8*)&tmp[srow][q3 * 16 + 8] = u1;
  __syncthreads();
  {  // V^T write: thread -> (d = t>>2, k-quarter kq = t&3)
    const int d = t >> 2, kq = t & 3;
    bf16x8 c0, c1;
#pragma unroll
    for (int i = 0; i < 8; ++i) {
      c0[i] = tmp[kq * 16 + i][d];
      c1[i] = tmp[kq * 16 + 8 + i][d];
    }
    __bf16* vrow = vtg + (((size_t)b * kMaxTiles + bx) * kKB + d) * kD;
    const int e = d & 7;
    *(bf16x8*)(vrow + (((2 * kq) ^ e) << 3)) = c0;
    *(bf16x8*)(vrow + (((2 * kq + 1) ^ e) << 3)) = c1;
  }
}

// ---------------- kernel 2: split-K flash attention, QB=128, fixed-max -------
// grid = (batch, split, qt): batch == blockIdx.x pins each batch to one XCD.
// Each wave serves 2 query-halves; every K/V A-frag LDS read feeds 2 MFMAs.
// Softmax denominator accumulated via ones-row MFMA (no VALU reduction).
__global__ __launch_bounds__(256, 4) void k_attn(const __bf16* __restrict__ xch,
                                                 const __bf16* __restrict__ vtg,
                                                 const int* __restrict__ counts,
                                                 float* __restrict__ pl,
                                                 __bf16* __restrict__ pacc) {
  const int b = blockIdx.x;
  const int s = blockIdx.y;
  const int qt = blockIdx.z;

  int cmax = 0;
#pragma unroll
  for (int i = 0; i < kBatch; ++i) cmax = max(cmax, counts[i]);
  const bool fb = cmax > kSlotCap;  // astronomically unlikely guard
  const int nS = fb ? 1 : (int)gridDim.y;
  if (fb && s > 0) return;

  const int count = counts[b];
  if (qt * kQB >= count) return;
  const int NTtot = (count + kKB - 1) >> 6;
  const int TPS = (NTtot + nS - 1) / nS;
  const int t0 = s * TPS;
  const int t1 = min(NTtot, t0 + TPS);

  const int tid = threadIdx.x;
  const int wave = tid >> 6;
  const int lane = tid & 63;
  const int lg = lane >> 4;  // lane group 0..3
  const int lr = lane & 15;  // lane row/col 0..15

  int qpos[2];
  bool qvalid[2];
  size_t sr[2];
#pragma unroll
  for (int h = 0; h < 2; ++h) {
    qpos[h] = qt * kQB + h * 64 + wave * 16 + lr;
    qvalid[h] = qpos[h] < count;
    sr[h] = slotrow(s, b, qpos[h], fb);
  }

  if (t0 >= t1) {  // empty split: identity partial (l=0, acc=0)
#pragma unroll
    for (int h = 0; h < 2; ++h) {
      if (qvalid[h]) {
        const bf16x4 z = (bf16x4)(__bf16)0.0f;
#pragma unroll
        for (int dt = 0; dt < 4; ++dt) *(bf16x4*)&pacc[sr[h] * kD + dt * 16 + lg * 4] = z;
        if (lg == 0) pl[sr[h]] = 0.0f;
      }
    }
    return;
  }

  const __bf16* __restrict__ xb = xch + (size_t)b * kSlotPad * kD;
  const __bf16* __restrict__ vb = vtg + (size_t)b * kMaxTiles * (kKB * kD);

  __shared__ __align__(16) __bf16 KhB[2][kKB * kD];  // K tiles (double buffer)
  __shared__ __align__(16) __bf16 VtB[2][kKB * kD];  // V^T tiles (double buffer)

  // ---- Q B-frags: lane holds Q[q][d=kt*32+lg*8+j] for both halves
  bf16x8 qh[2][2];
#pragma unroll
  for (int h = 0; h < 2; ++h) {
    const int qr = qvalid[h] ? qpos[h] : 0;
    const __bf16* qrow = xb + (size_t)qr * kD;
    const int f = fk(qr & 63);
#pragma unroll
    for (int kt = 0; kt < 2; ++kt)
      qh[h][kt] = *(const bf16x8*)(qrow + (((kt * 4 + lg) ^ f) << 3));
  }

  f32x4 acc[2][4];  // out^T per half: lane holds d = dt*16+4*lg+r, col q=lr
  f32x4 acc_l[2];   // denom via ones-row MFMA: row0 (lg==0) = sum_k p[k][q=lr]
#pragma unroll
  for (int h = 0; h < 2; ++h) {
#pragma unroll
    for (int i = 0; i < 4; ++i) acc[h][i] = (f32x4)0.0f;
    acc_l[h] = (f32x4)0.0f;
  }

  bf16x8 vone;  // ones-row A-frag
#pragma unroll
  for (int j = 0; j < 8; ++j) vone[j] = (lr == 0) ? (__bf16)1.0f : (__bf16)0.0f;

  // async staging: wave covers 2KB of each 8KB tile (2 x 1KB chunks per buffer)
  auto stage = [&](int t, int buf) {
    const size_t goff = (size_t)t * (kKB * kD);
    const int lo = lane * 8;
#pragma unroll
    for (int c = 0; c < 2; ++c) {
      const int eo = wave * 1024 + c * 512;
      gload16(xb + goff + eo + lo, &KhB[buf][eo]);
      gload16(vb + goff + eo + lo, &VtB[buf][eo]);
    }
  };

  stage(t0, 0);
  VBAR();

  int cur = 0;
  for (int t = t0; t < t1; ++t) {
    const bool havenext = (t + 1 < t1);
    if (havenext) stage(t + 1, cur ^ 1);  // DMA lands during compute

    const __bf16* Kh = &KhB[cur][0];
    const __bf16* Vt = &VtB[cur][0];

    // ---- QK: S' = K * Q^T; each ah feeds both halves
    f32x4 S_[2][2][2];  // [h][g][tt]
    __builtin_amdgcn_s_setprio(1);
#pragma unroll
    for (int g = 0; g < 2; ++g) {
#pragma unroll
      for (int tt = 0; tt < 2; ++tt) {
        const int krow = g * 32 + ((lr >> 2) << 3) + tt * 4 + (lr & 3);
        const int f = fk(krow);
        f32x4 s0 = (f32x4)0.0f, s1 = (f32x4)0.0f;
#pragma unroll
        for (int kt = 0; kt < 2; ++kt) {
          const bf16x8 ah = *(const bf16x8*)&Kh[(krow << 6) + (((kt * 4 + lg) ^ f) << 3)];
          s0 = MFMA_BF16(ah, qh[0][kt], s0);
          s1 = MFMA_BF16(ah, qh[1][kt], s1);
        }
        S_[0][g][tt] = s0;
        S_[1][g][tt] = s1;
      }
    }
    __builtin_amdgcn_s_setprio(0);

    // ---- fixed-max softmax: p = 2^(s*kC) (scores bounded; no max tracking)
    float p[2][2][2][4];
#pragma unroll
    for (int h = 0; h < 2; ++h)
#pragma unroll
      for (int g = 0; g < 2; ++g)
#pragma unroll
        for (int tt = 0; tt < 2; ++tt)
#pragma unroll
          for (int r = 0; r < 4; ++r)
            p[h][g][tt][r] = __builtin_amdgcn_exp2f(S_[h][g][tt][r] * kC);

    if (t == NTtot - 1 && (count & 63)) {  // zero-padded keys on last tile
      const int valid = count & 63;
#pragma unroll
      for (int h = 0; h < 2; ++h)
#pragma unroll
        for (int g = 0; g < 2; ++g)
#pragma unroll
          for (int tt = 0; tt < 2; ++tt)
#pragma unroll
            for (int r = 0; r < 4; ++r) {
              const int kl2 = g * 32 + lg * 8 + tt * 4 + r;
              if (kl2 >= valid) p[h][g][tt][r] = 0.0f;
            }
    }

    bf16x8 pf[2][2];  // [h][g]
#pragma unroll
    for (int h = 0; h < 2; ++h)
#pragma unroll
      for (int g = 0; g < 2; ++g)
#pragma unroll
        for (int tt = 0; tt < 2; ++tt)
#pragma unroll
          for (int r = 0; r < 4; ++r) pf[h][g][tt * 4 + r] = (__bf16)p[h][g][tt][r];

    // ---- PV: out^T += V^T * P'; denom via ones-row MFMA
    __builtin_amdgcn_s_setprio(1);
#pragma unroll
    for (int g = 0; g < 2; ++g) {
      acc_l[0] = MFMA_BF16(vone, pf[0][g], acc_l[0]);
      acc_l[1] = MFMA_BF16(vone, pf[1][g], acc_l[1]);
#pragma unroll
      for (int dt = 0; dt < 4; ++dt) {
        const int d = dt * 16 + lr;
        const bf16x8 vf =
            *(const bf16x8*)&Vt[(d << 6) + ((((g << 2) + lg) ^ (d & 7)) << 3)];
        acc[0][dt] = MFMA_BF16(vf, pf[0][g], acc[0][dt]);
        acc[1][dt] = MFMA_BF16(vf, pf[1][g], acc[1][dt]);
      }
    }
    __builtin_amdgcn_s_setprio(0);

    if (havenext) VBAR();  // DMA for t+1 complete + all waves done with cur
    cur ^= 1;
  }

  // ---- epilogue: bf16 partial acc + denom per half
#pragma unroll
  for (int h = 0; h < 2; ++h) {
    if (qvalid[h]) {
#pragma unroll
      for (int dt = 0; dt < 4; ++dt) {
        bf16x4 v;
#pragma unroll
        for (int r = 0; r < 4; ++r) v[r] = (__bf16)acc[h][dt][r];
        *(bf16x4*)&pacc[sr[h] * kD + dt * 16 + lg * 4] = v;
      }
      if (lg == 0) pl[sr[h]] = acc_l[h][0];
    }
  }
}

// ---------------- kernel 3: fused mean-fill + split-K reduce ------------------
// Fixed-max combine: out = (sum_s acc_s) / (sum_s l_s). Dword pacc loads
// (2 bf16 per load); 8 row-groups x 32 threads; float2 coalesced stores.
template <int TS>
__global__ __launch_bounds__(256) void k_post(const int* __restrict__ mask,
                                              const float* __restrict__ partial,
                                              const uint16_t* __restrict__ rank,
                                              const int* __restrict__ counts,
                                              const float* __restrict__ pl,
                                              const __bf16* __restrict__ pacc,
                                              float* __restrict__ out) {
  const int b = blockIdx.y;
  const int c = blockIdx.x;  // 128 chunks of 32 rows
  const int t = threadIdx.x;

  int cmax = 0;
#pragma unroll
  for (int i = 0; i < kBatch; ++i) cmax = max(cmax, counts[i]);
  const bool fb = cmax > kSlotCap;

  __shared__ float mean[64];
  __shared__ float winv[32];  // 1/L per token
  __shared__ int slotL[32];   // -1 = masked row

  if (t < 64) {  // phase 0: batch column mean
    float s = 0.0f;
    for (int p = 0; p < 32; ++p) s += partial[(b * 32 + p) * 64 + t];
    mean[t] = s * (1.0f / (float)kL);
  } else if (t < 96) {  // phase 1: per-token 1/L
    const int i = t - 64;
    const int r = c * 32 + i;
    if (mask[b * kL + r] == 0) {
      slotL[i] = -1;
    } else {
      const int slot = rank[b * kL + r];
      slotL[i] = slot;
      float L = 0.0f;
      if (!fb) {
#pragma unroll
        for (int s2 = 0; s2 < TS; ++s2)
          L += pl[(size_t)(s2 * kBatch + b) * kSlotCap + slot];
      } else {
        L = pl[(size_t)b * kL + slot];
      }
      winv[i] = 1.0f / L;
    }
  }
  __syncthreads();

  const int d0 = (t & 31) * 2;
  const int rg = t >> 5;  // row-group 0..7
#pragma unroll
  for (int it = 0; it < 4; ++it) {
    const int rl = it * 8 + rg;  // wave-uniform row-in-chunk
    const int slot = slotL[rl];
    float o0, o1;
    if (slot < 0) {
      o0 = mean[d0];
      o1 = mean[d0 + 1];
    } else if (!fb) {
      o0 = 0.0f;
      o1 = 0.0f;
#pragma unroll
      for (int s2 = 0; s2 < TS; ++s2) {
        const uint32_t v = *(const uint32_t*)&pacc[((size_t)(s2 * kBatch + b) * kSlotCap +
                                                    slot) * kD + d0];
        o0 += bf16hi_f(v & 0xFFFFu);
        o1 += bf16hi_f(v >> 16);
      }
      o0 *= winv[rl];
      o1 *= winv[rl];
    } else {
      const uint32_t v = *(const uint32_t*)&pacc[((size_t)b * kL + slot) * kD + d0];
      o0 = winv[rl] * bf16hi_f(v & 0xFFFFu);
      o1 = winv[rl] * bf16hi_f(v >> 16);
    }
    *(float2*)&out[((size_t)b * kL + c * 32 + rl) * kD + d0] = float2{o0, o1};
  }
}

}  // namespace

extern "C" void kernel_launch(void* const* d_in, const int* in_sizes, int n_in,
                              void* d_out, int out_size, void* d_ws, size_t ws_size,
                              hipStream_t stream) {
  const float* x = (const float*)d_in[0];
  const int* mask = (const int*)d_in[1];
  float* out = (float*)d_out;
  char* ws = (char*)d_ws;
  float* partial = (float*)(ws + kWsPartialOff);
  int* counts = (int*)(ws + kWsCountOff);
  uint16_t* rank = (uint16_t*)(ws + kWsRankOff);
  float* pl = (float*)(ws + kWsPlOff);
  __bf16* xch = (__bf16*)(ws + kWsXchOff);
  __bf16* vtg = (__bf16*)(ws + kWsVtgOff);
  __bf16* pacc = (__bf16*)(ws + kWsPaccOff);

  // ws_size ~268MB (round-7 fill evidence); S=4 layout ends well inside it
  int S = kSplits;
  while (S > 1 && ws_size < kWsPaccOff + (size_t)S * kBatch * kSlotCap * kD * 2) S >>= 1;

  k_prep<<<dim3(96, kBatch), dim3(256), 0, stream>>>(x, mask, partial, rank, counts,
                                                     xch, vtg);
  k_attn<<<dim3(kBatch, S, kL / kQB), dim3(256), 0, stream>>>(xch, vtg, counts, pl, pacc);
  switch (S) {
    case 4:
      k_post<4><<<dim3(128, kBatch), dim3(256), 0, stream>>>(mask, partial, rank, counts,
                                                             pl, pacc, out);
      break;
    case 2:
      k_post<2><<<dim3(128, kBatch), dim3(256), 0, stream>>>(mask, partial, rank, counts,
                                                             pl, pacc, out);
      break;
    default:
      k_post<1><<<dim3(128, kBatch), dim3(256), 0, stream>>>(mask, partial, rank, counts,
                                                             pl, pacc, out);
      break;
  }
}